// Round 4
// baseline (1058.580 us; speedup 1.0000x reference)
//
#include <hip/hip_runtime.h>

typedef __attribute__((ext_vector_type(8))) short short8;
typedef __attribute__((ext_vector_type(4))) short bf16x4;
typedef __attribute__((ext_vector_type(4))) float f32x4;

__device__ __forceinline__ f32x4 mfma16(short8 a, short8 b, f32x4 c) {
  return __builtin_amdgcn_mfma_f32_16x16x32_bf16(a, b, c, 0, 0, 0);
}

__device__ __forceinline__ short f2bf(float f) {  // RNE float->bf16
  union { float f; unsigned u; } v; v.f = f;
  unsigned r = (v.u + 0x7fffu + ((v.u >> 16) & 1u)) >> 16;
  return (short)r;
}

// ---------------- QKV GEMM: O[r][j] = sum_k X[r][k] * W[j][k] ----------------
// X: fp32 [M][768], W: fp32 [2304][768], O: bf16 [M][2304]. z=0 -> x, z=1 -> x_hsi.
__global__ __launch_bounds__(256) void gemm_qkv_k(
    const float* __restrict__ A0, const float* __restrict__ A1,
    const float* __restrict__ W,
    short* __restrict__ O0, short* __restrict__ O1) {
  __shared__ __align__(16) short As[128 * 32];
  __shared__ __align__(16) short Bs[128 * 32];
  const int tid = threadIdx.x;
  const int lane = tid & 63, wv = tid >> 6;
  const int l15 = lane & 15, q4 = lane >> 4;
  const int m0 = blockIdx.x * 128, n0 = blockIdx.y * 128;
  const float* A = blockIdx.z ? A1 : A0;
  short* O = blockIdx.z ? O1 : O0;
  const int wm = wv & 1, wn = wv >> 1;

  // fp32 staging: slot f = tid + i*256 -> row f>>3 (=fr+i*32), col4 (f&7)*4
  const int fr = tid >> 3;
  const int fc = (tid & 7) * 4;

  f32x4 acc[4][4] = {};
  for (int k0 = 0; k0 < 768; k0 += 32) {
    float4 av[4], bv[4];
#pragma unroll
    for (int i = 0; i < 4; ++i) {
      av[i] = *(const float4*)(A + (long)(m0 + fr + i * 32) * 768 + k0 + fc);
      bv[i] = *(const float4*)(W + (long)(n0 + fr + i * 32) * 768 + k0 + fc);
    }
    __syncthreads();  // previous iteration's readers done
#pragma unroll
    for (int i = 0; i < 4; ++i) {
      *(bf16x4*)&As[(fr + i * 32) * 32 + fc] =
          bf16x4{f2bf(av[i].x), f2bf(av[i].y), f2bf(av[i].z), f2bf(av[i].w)};
      *(bf16x4*)&Bs[(fr + i * 32) * 32 + fc] =
          bf16x4{f2bf(bv[i].x), f2bf(bv[i].y), f2bf(bv[i].z), f2bf(bv[i].w)};
    }
    __syncthreads();
    short8 af[4], bf[4];
#pragma unroll
    for (int i = 0; i < 4; ++i)
      af[i] = *(const short8*)&As[(wm * 64 + i * 16 + l15) * 32 + q4 * 8];
#pragma unroll
    for (int j = 0; j < 4; ++j)
      bf[j] = *(const short8*)&Bs[(wn * 64 + j * 16 + l15) * 32 + q4 * 8];
#pragma unroll
    for (int i = 0; i < 4; ++i)
#pragma unroll
      for (int j = 0; j < 4; ++j)
        acc[i][j] = mfma16(af[i], bf[j], acc[i][j]);
  }
#pragma unroll
  for (int i = 0; i < 4; ++i)
#pragma unroll
    for (int j = 0; j < 4; ++j) {
      const int col = n0 + wn * 64 + j * 16 + l15;
#pragma unroll
      for (int r = 0; r < 4; ++r) {
        const int row = m0 + wm * 64 + i * 16 + q4 * 4 + r;
        O[(long)row * 2304 + col] = f2bf(acc[i][j][r]);
      }
    }
}

// ---------------- Attention (ws bf16 in, ws bf16 out) ----------------
// One block = 64 queries of one (b,h,kind); wave = 16 queries.
// NK=128: mt (t=0..1). NK=384: t=0..3 -> s (qkvx), t=4..7 -> s_hsi (qkvh).
template <int NK>
__global__ __launch_bounds__(256) void attn_k(
    const short* __restrict__ qkvx, const short* __restrict__ qkvh,
    short* __restrict__ omt, short* __restrict__ os, short* __restrict__ osh) {
  constexpr int NT = NK / 16;
  constexpr int KT = NK / 64;
  constexpr int PSTR = NK + 8;
  constexpr int T = (NK == 128) ? 2 : 8;
  __shared__ __align__(16) short kv[64 * 72];     // K tile, then V^T tile
  __shared__ __align__(16) short sp[64 * PSTR];   // P (unnormalized), bf16

  const int tid = threadIdx.x, lane = tid & 63, wv = tid >> 6;
  const int l15 = lane & 15, q4 = lane >> 4;
  const int bx = blockIdx.x;
  const int b = bx / (12 * T);
  const int rr = bx % (12 * T);
  const int h = rr / T, t = rr % T;

  const short* src;
  short* outb;
  int q0;
  if (NK == 128) {
    src = qkvx;
    outb = omt + ((long)b * 128 + t * 64) * 768 + h * 64;
    q0 = t * 64;
  } else {
    const int tt = t & 3;
    const bool hs = t >= 4;
    src = hs ? qkvh : qkvx;
    outb = (hs ? osh : os) + ((long)b * 256 + tt * 64) * 768 + h * 64;
    q0 = 128 + tt * 64;
  }
  const short* qb = src + ((long)(b * 384 + q0 + wv * 16)) * 2304 + h * 64;
  const short* kb = src + (long)b * 384 * 2304 + 768 + h * 64;
  const short* vb = kb + 768;

  short8 qf0 = *(const short8*)(qb + (long)l15 * 2304 + q4 * 8);
  short8 qf1 = *(const short8*)(qb + (long)l15 * 2304 + 32 + q4 * 8);

  // ---- S = Q K^T ----
  f32x4 sacc[NT] = {};
#pragma unroll
  for (int kt = 0; kt < KT; ++kt) {
#pragma unroll
    for (int i = 0; i < 2; ++i) {
      const int c2 = tid + i * 256;
      const int key = c2 >> 3, dg = c2 & 7;
      short8 kvv = *(const short8*)(kb + (long)(kt * 64 + key) * 2304 + dg * 8);
      *(short8*)&kv[key * 72 + dg * 8] = kvv;
    }
    __syncthreads();
#pragma unroll
    for (int j = 0; j < 4; ++j) {
      short8 kf0 = *(const short8*)&kv[(j * 16 + l15) * 72 + q4 * 8];
      short8 kf1 = *(const short8*)&kv[(j * 16 + l15) * 72 + 32 + q4 * 8];
      sacc[kt * 4 + j] = mfma16(qf0, kf0, sacc[kt * 4 + j]);
      sacc[kt * 4 + j] = mfma16(qf1, kf1, sacc[kt * 4 + j]);
    }
    __syncthreads();
  }

  // ---- softmax ----
  const float scale = 0.125f;
  float mx[4] = {-3e38f, -3e38f, -3e38f, -3e38f};
#pragma unroll
  for (int nt = 0; nt < NT; ++nt)
#pragma unroll
    for (int r = 0; r < 4; ++r) mx[r] = fmaxf(mx[r], sacc[nt][r]);
#pragma unroll
  for (int r = 0; r < 4; ++r) {
    mx[r] = fmaxf(mx[r], __shfl_xor(mx[r], 1));
    mx[r] = fmaxf(mx[r], __shfl_xor(mx[r], 2));
    mx[r] = fmaxf(mx[r], __shfl_xor(mx[r], 4));
    mx[r] = fmaxf(mx[r], __shfl_xor(mx[r], 8));
  }
  float sm[4] = {0.f, 0.f, 0.f, 0.f};
#pragma unroll
  for (int nt = 0; nt < NT; ++nt)
#pragma unroll
    for (int r = 0; r < 4; ++r) {
      float e = __expf((sacc[nt][r] - mx[r]) * scale);
      sm[r] += e;
      sp[(wv * 16 + q4 * 4 + r) * PSTR + nt * 16 + l15] = f2bf(e);
    }
#pragma unroll
  for (int r = 0; r < 4; ++r) {
    sm[r] += __shfl_xor(sm[r], 1);
    sm[r] += __shfl_xor(sm[r], 2);
    sm[r] += __shfl_xor(sm[r], 4);
    sm[r] += __shfl_xor(sm[r], 8);
  }

  // ---- O = P V ----
  f32x4 oacc[4] = {};
#pragma unroll
  for (int kt = 0; kt < KT; ++kt) {
    __syncthreads();
#pragma unroll
    for (int i = 0; i < 2; ++i) {
      const int c2 = tid + i * 256;
      const int key = c2 >> 3, dg = c2 & 7;
      short8 vvv = *(const short8*)(vb + (long)(kt * 64 + key) * 2304 + dg * 8);
#pragma unroll
      for (int e = 0; e < 8; ++e) kv[(dg * 8 + e) * 72 + key] = vvv[e];
    }
    __syncthreads();
#pragma unroll
    for (int ks = 0; ks < 2; ++ks) {
      short8 pf = *(const short8*)&sp[(wv * 16 + l15) * PSTR + kt * 64 + ks * 32 + q4 * 8];
#pragma unroll
      for (int n2 = 0; n2 < 4; ++n2) {
        short8 vf = *(const short8*)&kv[(n2 * 16 + l15) * 72 + ks * 32 + q4 * 8];
        oacc[n2] = mfma16(pf, vf, oacc[n2]);
      }
    }
  }

  short* ob = outb + wv * 16 * 768;
#pragma unroll
  for (int r = 0; r < 4; ++r) {
    const float inv = 1.f / sm[r];
#pragma unroll
    for (int n2 = 0; n2 < 4; ++n2)
      ob[(q4 * 4 + r) * 768 + n2 * 16 + l15] = f2bf(oacc[n2][r] * inv);
  }
}

// ------- Proj GEMM: out[r][j] = sum_k Xa[r][k]*Pw[j][k] + pb[j] (fp32 out) -----
__global__ __launch_bounds__(256) void gemm_proj_k(
    const short* __restrict__ mt, const short* __restrict__ sA,
    const short* __restrict__ sh,
    const float* __restrict__ W, const float* __restrict__ bias,
    float* __restrict__ out, int cb0) {
  __shared__ __align__(16) short As[128 * 32];
  __shared__ __align__(16) short Bs[128 * 32];
  const int tid = threadIdx.x;
  const int lane = tid & 63, wv = tid >> 6;
  const int l15 = lane & 15, q4 = lane >> 4;
  const int m0 = blockIdx.x * 128, n0 = blockIdx.y * 128;
  const short* s = blockIdx.z ? sh : sA;
  const int wm = wv & 1, wn = wv >> 1;

  // A (bf16 ws): 2 short8 slots per thread
  const int sr0 = tid >> 2, sc0 = (tid & 3) * 8;
  const int sr1 = (tid + 256) >> 2, sc1 = sc0;
  const int ra = m0 + sr0, rb = m0 + sr1;
  const int ba_ = ra / 384, na = ra % 384;
  const int bb_ = rb / 384, nb = rb % 384;
  const short* ap0 = (na < 128) ? (mt + ((long)ba_ * 128 + na) * 768)
                                : (s + ((long)ba_ * 256 + (na - 128)) * 768);
  const short* ap1 = (nb < 128) ? (mt + ((long)bb_ * 128 + nb) * 768)
                                : (s + ((long)bb_ * 256 + (nb - 128)) * 768);
  // W (fp32): 4 float4 slots per thread
  const int fr = tid >> 3;
  const int fc = (tid & 7) * 4;

  f32x4 acc[4][4] = {};
  for (int k0 = 0; k0 < 768; k0 += 32) {
    short8 a0 = *(const short8*)(ap0 + k0 + sc0);
    short8 a1 = *(const short8*)(ap1 + k0 + sc1);
    float4 bv[4];
#pragma unroll
    for (int i = 0; i < 4; ++i)
      bv[i] = *(const float4*)(W + (long)(n0 + fr + i * 32) * 768 + k0 + fc);
    __syncthreads();
    *(short8*)&As[sr0 * 32 + sc0] = a0;
    *(short8*)&As[sr1 * 32 + sc1] = a1;
#pragma unroll
    for (int i = 0; i < 4; ++i)
      *(bf16x4*)&Bs[(fr + i * 32) * 32 + fc] =
          bf16x4{f2bf(bv[i].x), f2bf(bv[i].y), f2bf(bv[i].z), f2bf(bv[i].w)};
    __syncthreads();
    short8 af[4], bf[4];
#pragma unroll
    for (int i = 0; i < 4; ++i)
      af[i] = *(const short8*)&As[(wm * 64 + i * 16 + l15) * 32 + q4 * 8];
#pragma unroll
    for (int j = 0; j < 4; ++j)
      bf[j] = *(const short8*)&Bs[(wn * 64 + j * 16 + l15) * 32 + q4 * 8];
#pragma unroll
    for (int i = 0; i < 4; ++i)
#pragma unroll
      for (int j = 0; j < 4; ++j)
        acc[i][j] = mfma16(af[i], bf[j], acc[i][j]);
  }
#pragma unroll
  for (int j = 0; j < 4; ++j) {
    const int col = n0 + wn * 64 + j * 16 + l15;
    const float bvv = bias[col];
#pragma unroll
    for (int i = 0; i < 4; ++i)
#pragma unroll
      for (int r = 0; r < 4; ++r) {
        const int row = m0 + wm * 64 + i * 16 + q4 * 4 + r;
        out[(long)blockIdx.z * 18874368 + ((long)cb0 * 384 + row) * 768 + col] =
            acc[i][j][r] + bvv;
      }
  }
}

extern "C" void kernel_launch(void* const* d_in, const int* in_sizes, int n_in,
                              void* d_out, int out_size, void* d_ws, size_t ws_size,
                              hipStream_t stream) {
  (void)in_sizes; (void)n_in; (void)out_size;
  const float* x  = (const float*)d_in[0];
  const float* xh = (const float*)d_in[1];
  const float* qw = (const float*)d_in[2];
  const float* pw = (const float*)d_in[3];
  const float* pb = (const float*)d_in[4];
  float* out = (float*)d_out;

  // per-batch ws bytes (all bf16): 2 QKV tensors + 3 attention outputs
  const long perBatch = (2L * 384 * 2304 + 640L * 768) * 2;  // 4,521,984
  int CB = 64;
  while (CB > 1 && (long)CB * perBatch > (long)ws_size) CB >>= 1;

  char* ws = (char*)d_ws;
  const long qkvSz = (long)CB * 384 * 2304 * 2;
  const long mtSz  = (long)CB * 128 * 768 * 2;
  const long sSz   = (long)CB * 256 * 768 * 2;
  short* qkvx = (short*)ws;
  short* qkvh = (short*)(ws + qkvSz);
  short* amt  = (short*)(ws + 2 * qkvSz);
  short* as_  = (short*)(ws + 2 * qkvSz + mtSz);
  short* ash  = (short*)(ws + 2 * qkvSz + mtSz + sSz);

  const int nch = 64 / CB;
  for (int c = 0; c < nch; ++c) {
    const int cb0 = c * CB;
    const float* xA = x  + (long)cb0 * 384 * 768;
    const float* xB = xh + (long)cb0 * 384 * 768;
    dim3 g1(CB * 3, 18, 2);
    gemm_qkv_k<<<g1, 256, 0, stream>>>(xA, xB, qw, qkvx, qkvh);
    attn_k<128><<<CB * 12 * 2, 256, 0, stream>>>(qkvx, qkvh, amt, as_, ash);
    attn_k<384><<<CB * 12 * 8, 256, 0, stream>>>(qkvx, qkvh, amt, as_, ash);
    dim3 g3(CB * 3, 6, 2);
    gemm_proj_k<<<g3, 256, 0, stream>>>(amt, as_, ash, pw, pb, out, cb0);
  }
}